// Round 2
// baseline (176.560 us; speedup 1.0000x reference)
//
#include <hip/hip_runtime.h>
#include <hip/hip_bf16.h>
#include <math.h>

#define S_LEN 2048
#define DIM   1024
#define NH    16
#define NKVH  4
#define HD    64
#define KVDIM 256

typedef __hip_bfloat16 bf16;
typedef __attribute__((ext_vector_type(8))) short short8;   // 8 bf16 (4 VGPRs)
typedef __attribute__((ext_vector_type(4))) float f32x4;

#define GLOBAL_AS __attribute__((address_space(1)))
#define LDS_AS    __attribute__((address_space(3)))

__device__ __forceinline__ void gload_lds16(const bf16* g, bf16* l) {
    // LDS dest = wave-uniform base + lane*16 (hardware rule); caller passes
    // the wave's base, identical across lanes.
    __builtin_amdgcn_global_load_lds((const GLOBAL_AS void*)g, (LDS_AS void*)l,
                                     16, 0, 0);
}

// ---------------------------------------------------------------------------
// One-dispatch fp32 -> bf16 cast of all six inputs (grid.y = which) plus a
// 7th slice (grid.y==6) that builds the rotary cos/sin table once
// (bit-identical math to the original per-lane computation).
// ---------------------------------------------------------------------------
__global__ __launch_bounds__(256) void cast6(
    const float* __restrict__ x,  const float* __restrict__ Wq,
    const float* __restrict__ Wk, const float* __restrict__ Wv,
    const float* __restrict__ Wg, const float* __restrict__ Wo,
    bf16* __restrict__ xb,  bf16* __restrict__ Wqb,
    bf16* __restrict__ Wkb, bf16* __restrict__ Wvb,
    bf16* __restrict__ Wgb, bf16* __restrict__ Wob,
    float* __restrict__ rc, float* __restrict__ rs) {
    if (blockIdx.y == 6) {
        const int idx = blockIdx.x * 256 + threadIdx.x;
        if (idx < S_LEN * 32) {
            const int s = idx >> 5, i = idx & 31;
            float af  = (float)(((double)(2 * i) / 64.0) * 3.14159265358979323846);
            float ang = (float)s * af;
            float radius = 1.0f / (1.0f + 0.01f * (float)s);
            rc[idx] = radius * (float)cos((double)ang);
            rs[idx] = radius * (float)sin((double)ang);
        }
        return;
    }
    const float* s; bf16* d; int n;
    switch (blockIdx.y) {
        case 0: s = x;  d = xb;  n = S_LEN * DIM; break;
        case 1: s = Wq; d = Wqb; n = DIM * DIM;   break;
        case 2: s = Wk; d = Wkb; n = KVDIM * DIM; break;
        case 3: s = Wv; d = Wvb; n = KVDIM * DIM; break;
        case 4: s = Wg; d = Wgb; n = KVDIM * DIM; break;
        default: s = Wo; d = Wob; n = DIM * DIM;  break;
    }
    for (int i = (blockIdx.x * 256 + threadIdx.x) * 4; i < n; i += gridDim.x * 1024) {
        float4 v = *(const float4*)(s + i);
        d[i]     = __float2bfloat16(v.x);
        d[i + 1] = __float2bfloat16(v.y);
        d[i + 2] = __float2bfloat16(v.z);
        d[i + 3] = __float2bfloat16(v.w);
    }
}

// ---------------------------------------------------------------------------
// bf16 MFMA GEMM core, m97 structure: C[M,N] = A[M,K]*B[N,K]^T, fp32 out.
// BM = 32*MREP rows x BN = 32*NREP cols per block, BK = 32, 4 waves in a
// 2x2 grid; each wave owns a (16*MREP)x(16*NREP) quadrant with an
// MREP x NREP fragment accumulator. Per wave per K-step: MREP+NREP
// ds_read_b128 feed MREP*NREP MFMAs (no redundant B reads across waves).
// BK=32 -> 64-byte LDS rows -> fragment reads hit the 8-lanes-per-bank-group
// ds_read_b128 floor with a LINEAR layout: no swizzle needed on either side,
// so global_load_lds staging is linear too (rule #21 trivially satisfied).
// ---------------------------------------------------------------------------
template<int MREP, int NREP>
__device__ __forceinline__ void gemm_core128(
    const bf16* __restrict__ A, const bf16* __restrict__ B,
    float* __restrict__ C, int bm, int bn, int N, int K) {
    constexpr int BM = MREP * 32;
    constexpr int BN = NREP * 32;
    __shared__ bf16 As[BM * 32];           // [BM][32] linear, 64 B rows
    __shared__ bf16 Bs[BN * 32];
    const int tid  = threadIdx.x;
    const int w    = tid >> 6;
    const int lane = tid & 63;
    const int quad = lane >> 4;
    const int lm   = lane & 15;
    const int wr   = w >> 1, wc = w & 1;
    // Staging: dest byte = tid*16 + i*4096 -> row = tid/4 + i*64, seg = tid&3
    const int srow = tid >> 2;
    const int scol = (tid & 3) << 3;       // bf16 elements
    const bf16* aSrc = A + (size_t)(bm + srow) * K + scol;
    const bf16* bSrc = B + (size_t)(bn + srow) * K + scol;
    bf16* aDst = As + w * 512;             // wave-uniform bases (byte w*1024)
    bf16* bDst = Bs + w * 512;
    constexpr int ALOADS = BM / 64;        // 2
    constexpr int BLOADS = BN / 64;        // 2 (BN=128) or 1 (BN=64)

    f32x4 acc[MREP][NREP] = {};
    int aoff[MREP], boff[NREP];
    #pragma unroll
    for (int m = 0; m < MREP; ++m)
        aoff[m] = (wr * (16 * MREP) + m * 16 + lm) * 32 + quad * 8;
    #pragma unroll
    for (int n = 0; n < NREP; ++n)
        boff[n] = (wc * (16 * NREP) + n * 16 + lm) * 32 + quad * 8;

    for (int k0 = 0; k0 < K; k0 += 32) {
        #pragma unroll
        for (int i = 0; i < ALOADS; ++i)
            gload_lds16(aSrc + (size_t)(i * 64) * K + k0, aDst + i * 2048);
        #pragma unroll
        for (int i = 0; i < BLOADS; ++i)
            gload_lds16(bSrc + (size_t)(i * 64) * K + k0, bDst + i * 2048);
        __syncthreads();                   // compiler drains vmcnt before barrier
        short8 af[MREP], bfr[NREP];
        #pragma unroll
        for (int m = 0; m < MREP; ++m) af[m]  = *(const short8*)&As[aoff[m]];
        #pragma unroll
        for (int n = 0; n < NREP; ++n) bfr[n] = *(const short8*)&Bs[boff[n]];
        #pragma unroll
        for (int m = 0; m < MREP; ++m)
            #pragma unroll
            for (int n = 0; n < NREP; ++n)
                acc[m][n] = __builtin_amdgcn_mfma_f32_16x16x32_bf16(
                    af[m], bfr[n], acc[m][n], 0, 0, 0);
        __syncthreads();
    }
    #pragma unroll
    for (int m = 0; m < MREP; ++m) {
        const int r0 = bm + wr * (16 * MREP) + m * 16 + quad * 4;
        #pragma unroll
        for (int n = 0; n < NREP; ++n) {
            const int col = bn + wc * (16 * NREP) + n * 16 + lm;
            #pragma unroll
            for (int i = 0; i < 4; ++i)
                C[(size_t)(r0 + i) * N + col] = acc[m][n][i];
        }
    }
}

// Fused Q+K+V+G projection: one dispatch, 128x128 tiles, grid (14, 16).
__global__ __launch_bounds__(256) void gemm_qkvg(
    const bf16* __restrict__ xb, const bf16* __restrict__ Wqb,
    const bf16* __restrict__ Wkb, const bf16* __restrict__ Wvb,
    const bf16* __restrict__ Wgb, float* __restrict__ Qp,
    float* __restrict__ KVG) {
    const int cx = blockIdx.x;
    const bf16* B; float* C; int bn, N;
    if (cx < 8) { B = Wqb; C = Qp; bn = cx * 128; N = DIM; }
    else {
        const int t = cx - 8;
        const int wsel = t >> 1;
        B = (wsel == 0) ? Wkb : (wsel == 1) ? Wvb : Wgb;
        C = KVG + (size_t)wsel * S_LEN * KVDIM;
        bn = (t & 1) * 128; N = KVDIM;
    }
    gemm_core128<4, 4>(xb, B, C, blockIdx.y * 128, bn, N, DIM);
}

// Output projection: 128x64 tiles -> grid (16, 16) = 256 blocks (1/CU).
__global__ __launch_bounds__(256) void gemm_out(
    const bf16* __restrict__ Yb, const bf16* __restrict__ Wob,
    float* __restrict__ C) {
    gemm_core128<4, 2>(Yb, Wob, C, blockIdx.y * 128, blockIdx.x * 64, DIM, DIM);
}

// ---------------------------------------------------------------------------
// Postproc -> Qb (row-major bf16) and B-fragment-PACKED Kpk/Vpk.
// Rotary cos/sin read from the precomputed table (bit-identical values).
// ---------------------------------------------------------------------------
__device__ __forceinline__ float rms_rot_val(
    const float* __restrict__ p, int s, int lane, float gain,
    const float* __restrict__ rc, const float* __restrict__ rs) {
    float x = p[lane];
    float ss = x * x;
    #pragma unroll
    for (int o = 32; o > 0; o >>= 1) ss += __shfl_xor(ss, o);
    float n = x * rsqrtf(ss * (1.0f/64.0f) + 1.1920928955078125e-7f);
    float other = __shfl_xor(n, 32);
    int i = lane & 31;
    float c  = rc[s * 32 + i];
    float sn = rs[s * 32 + i];
    return (n * c + ((lane < 32) ? other * sn : -other * sn)) * gain;
}

__global__ __launch_bounds__(64) void postproc_pk(
    const float* __restrict__ Qp, const float* __restrict__ Kp,
    const float* __restrict__ Vp, const float* __restrict__ Gp,
    bf16* __restrict__ Qb, bf16* __restrict__ Kpk, bf16* __restrict__ Vpk,
    const float* __restrict__ qgain,
    const float* __restrict__ rc, const float* __restrict__ rs) {
    const int s = blockIdx.x;
    const int unit = blockIdx.y;
    const int lane = threadIdx.x;
    const int half = lane >> 5, d32 = lane & 31;
    const int kb = s >> 5;
    if (unit < NH) {
        float v = rms_rot_val(Qp + (size_t)s * DIM + unit * HD, s, lane, qgain[unit], rc, rs);
        Qb[(size_t)s * DIM + unit * HD + lane] = __float2bfloat16(v);
    } else if (unit < NH + NKVH) {
        const int kvh = unit - NH;
        float v = rms_rot_val(Kp + (size_t)s * KVDIM + kvh * HD, s, lane, 1.0f, rc, rs);
        const size_t ki = (((((size_t)(kvh*2 + half)*64 + kb)*2 + ((s&31)>>4))*64)
                           + (d32>>3)*16 + (s&15))*8 + (d32&7);
        Kpk[ki] = __float2bfloat16(v);
    } else {
        const int kvh = unit - NH - NKVH;
        const float* v = Vp + (size_t)s * KVDIM + kvh * HD;
        const float* g = Gp + (size_t)s * KVDIM + kvh * HD;
        float gv = g[lane];
        float val = v[lane] / (1.0f + __expf(-gv));
        const size_t vi = (((((size_t)(kvh*2 + half)*64 + kb)*2 + (d32>>4))*64)
                           + ((s&31)>>3)*16 + (d32&15))*8 + (s&7);
        Vpk[vi] = __float2bfloat16(val);
    }
}

// ---------------------------------------------------------------------------
// MFMA flash attention v3 (unchanged, verified): 1 wave per block, grid 4096.
// ---------------------------------------------------------------------------
__global__ __launch_bounds__(64, 4) void attn_mfma(
    const bf16* __restrict__ Qb, const bf16* __restrict__ Kpk,
    const bf16* __restrict__ Vpk, float* __restrict__ Ao) {
    __shared__ short PW[640];             // 16 rows x 40 shorts
    const int id    = blockIdx.x;
    const int qtile = 127 - (id >> 5);
    const int hh    = id & 31;
    const int h     = hh >> 1;
    const int half  = hh & 1;
    const int kvh   = h >> 2;
    const int lane  = threadIdx.x;
    const int quad  = lane >> 4;
    const int m     = lane & 15;
    bf16* PWb = (bf16*)PW;

    const int qrow = qtile * 16 + m;
    short8 qf = *(const short8*)(Qb + (size_t)qrow * DIM + h * HD + half * 32 + quad * 8);

    const bf16* kbase = Kpk + (size_t)(kvh * 2 + half) * 64 * 1024 + lane * 8;
    const bf16* vbase = Vpk + (size_t)(kvh * 2 + half) * 64 * 1024 + lane * 8;

    f32x4 o0 = {}, o1 = {};
    float lpart[4] = {0.f, 0.f, 0.f, 0.f};
    const float scale = 0.17677669529663687f;   // 1/sqrt(32)
    const int rbase = qtile * 16 + quad * 4;
    const int nkt = (qtile >> 1) + 1;

    for (int kb = 0; kb < nkt; ++kb) {
        short8 kf0 = *(const short8*)(kbase + kb * 1024);
        short8 kf1 = *(const short8*)(kbase + kb * 1024 + 512);
        f32x4 s0 = {}, s1 = {};
        s0 = __builtin_amdgcn_mfma_f32_16x16x32_bf16(qf, kf0, s0, 0, 0, 0);
        s1 = __builtin_amdgcn_mfma_f32_16x16x32_bf16(qf, kf1, s1, 0, 0, 0);
        short8 vtf0 = *(const short8*)(vbase + kb * 1024);
        short8 vtf1 = *(const short8*)(vbase + kb * 1024 + 512);
        const int kg = kb * 32 + m;
        #pragma unroll
        for (int r = 0; r < 4; ++r) {
            const int rg = rbase + r;
            const float p0 = (kg > rg)      ? 0.f : __expf(s0[r] * scale);
            const float p1 = (kg + 16 > rg) ? 0.f : __expf(s1[r] * scale);
            lpart[r] += p0 + p1;
            PWb[(quad * 4 + r) * 40 + m]      = __float2bfloat16(p0);
            PWb[(quad * 4 + r) * 40 + 16 + m] = __float2bfloat16(p1);
        }
        asm volatile("s_waitcnt lgkmcnt(0)" ::: "memory");
        short8 pf = *(const short8*)&PW[m * 40 + quad * 8];
        o0 = __builtin_amdgcn_mfma_f32_16x16x32_bf16(pf, vtf0, o0, 0, 0, 0);
        o1 = __builtin_amdgcn_mfma_f32_16x16x32_bf16(pf, vtf1, o1, 0, 0, 0);
    }

    #pragma unroll
    for (int r = 0; r < 4; ++r) {
        float v = lpart[r];
        v += __shfl_xor(v, 1);
        v += __shfl_xor(v, 2);
        v += __shfl_xor(v, 4);
        v += __shfl_xor(v, 8);
        lpart[r] = 1.f / v;
    }
    #pragma unroll
    for (int r = 0; r < 4; ++r) {
        float* op = Ao + (size_t)(rbase + r) * DIM + h * HD + half * 32;
        op[m]      = o0[r] * lpart[r];
        op[16 + m] = o1[r] * lpart[r];
    }
}

// ---------------------------------------------------------------------------
// Combine -> bf16 Y (verified)
// ---------------------------------------------------------------------------
__global__ __launch_bounds__(256) void combine_kernel(
    const float* __restrict__ A, const float* __restrict__ lambda_p,
    bf16* __restrict__ Y) {
    const int idx = blockIdx.x * 256 + threadIdx.x;
    const int c = idx & (DIM - 1);
    const int s = idx >> 10;
    const int hh = c >> 6;
    const int d = c & 63;
    const float* base = A + (size_t)s * DIM + hh * HD;
    const float lam = lambda_p[hh];
    float y;
    if (d < 32) y = base[d]      - lam * base[d + 32];
    else        y = base[d - 32] + lam * base[d];
    Y[idx] = __float2bfloat16(y);
}

// ---------------------------------------------------------------------------
// Workspace (31.5 MB):
//  0-8    Qp fp32 (dead after postproc) -> Yb bf16 overlays 0-4
//  8-14   KVG fp32 (Kp 8-10, Vp 10-12, Gp 12-14; dead after postproc)
//  14-22  Ao fp32 (written at step 3) -- rotary table borrows 14-14.5 during
//         steps 0-2 (rc 256KB @14MB, rs 256KB @14.25MB; dead before attn)
//  22-26  xb bf16 (dead after gemm_qkvg) -> Qb overlays
//  26-28  Wqb (dead after gemm) -> Kpk 26-27, Vpk 27-28 overlay
//  28-29.5 Wkb/Wvb/Wgb | 29.5-31.5 Wob (live till gemm_out)
// ---------------------------------------------------------------------------
extern "C" void kernel_launch(void* const* d_in, const int* in_sizes, int n_in,
                              void* d_out, int out_size, void* d_ws, size_t ws_size,
                              hipStream_t stream) {
    const float* x  = (const float*)d_in[0];
    const float* Wq = (const float*)d_in[1];
    const float* Wk = (const float*)d_in[2];
    const float* Wv = (const float*)d_in[3];
    const float* Wg = (const float*)d_in[4];
    const float* Wo = (const float*)d_in[5];
    const float* qg = (const float*)d_in[6];
    const float* lp = (const float*)d_in[7];
    float* out = (float*)d_out;

    char* ws = (char*)d_ws;
    float* Qp  = (float*)(ws);
    float* KVG = (float*)(ws + (8u  << 20));
    float* Kp  = KVG;
    float* Vp  = KVG + (size_t)S_LEN * KVDIM;
    float* Gp  = KVG + (size_t)2 * S_LEN * KVDIM;
    float* Ao  = (float*)(ws + (14u << 20));
    float* rc  = (float*)(ws + (14u << 20));            // borrows Ao (dead)
    float* rs  = (float*)(ws + (14u << 20) + (256u << 10));
    bf16* xb   = (bf16*)(ws + (22u << 20));
    bf16* Wqb  = (bf16*)(ws + (26u << 20));
    bf16* Wkb  = (bf16*)(ws + (28u << 20));
    bf16* Wvb  = (bf16*)(ws + (28u << 20) + (512u << 10));
    bf16* Wgb  = (bf16*)(ws + (29u << 20));
    bf16* Wob  = (bf16*)(ws + (29u << 20) + (512u << 10));
    bf16* Qb   = (bf16*)(ws + (22u << 20));  // overlays dead xb
    bf16* Kpk  = (bf16*)(ws + (26u << 20));  // overlays dead Wqb
    bf16* Vpk  = (bf16*)(ws + (27u << 20));
    bf16* Yb   = (bf16*)ws;                  // overlays dead Qp

    // 0. One-dispatch cast of all inputs to bf16 + rotary table build
    cast6<<<dim3(512, 7), 256, 0, stream>>>(x, Wq, Wk, Wv, Wg, Wo,
                                            xb, Wqb, Wkb, Wvb, Wgb, Wob, rc, rs);

    // 1. Fused Q/K/V/G projection (one dispatch, 224 blocks of 128x128)
    gemm_qkvg<<<dim3(14, S_LEN/128), 256, 0, stream>>>(xb, Wqb, Wkb, Wvb, Wgb, Qp, KVG);

    // 2. RMSNorm + rotary + gate -> Qb + packed Kpk/Vpk
    postproc_pk<<<dim3(S_LEN, NH + 2*NKVH), 64, 0, stream>>>(
        Qp, Kp, Vp, Gp, Qb, Kpk, Vpk, qg, rc, rs);

    // 3. MFMA flash attention (4096 single-wave blocks, coalesced frags)
    attn_mfma<<<4096, 64, 0, stream>>>(Qb, Kpk, Vpk, Ao);

    // 4. Lambda combine -> bf16 Y (overlays dead Qp)
    combine_kernel<<<S_LEN * DIM / 256, 256, 0, stream>>>(Ao, lp, Yb);

    // 5. MFMA output projection -> fp32 out (256 blocks of 128x64)
    gemm_out<<<dim3(DIM/64, S_LEN/128), 256, 0, stream>>>(Yb, Wob, out);
}

// Round 3
// 149.256 us; speedup vs baseline: 1.1829x; 1.1829x over previous
//
#include <hip/hip_runtime.h>
#include <hip/hip_bf16.h>
#include <math.h>

#define S_LEN 2048
#define DIM   1024
#define NH    16
#define NKVH  4
#define HD    64
#define KVDIM 256

typedef __hip_bfloat16 bf16;
typedef __attribute__((ext_vector_type(8))) short short8;   // 8 bf16 (4 VGPRs)
typedef __attribute__((ext_vector_type(4))) float f32x4;

#define GLOBAL_AS __attribute__((address_space(1)))
#define LDS_AS    __attribute__((address_space(3)))

__device__ __forceinline__ void gload_lds16(const bf16* g, bf16* l) {
    // LDS dest = wave-uniform base + lane*16 (hardware rule).
    __builtin_amdgcn_global_load_lds((const GLOBAL_AS void*)g, (LDS_AS void*)l,
                                     16, 0, 0);
}

// ---------------------------------------------------------------------------
// One-dispatch fp32 -> bf16 cast of all six inputs (grid.y = which) plus a
// 7th slice (grid.y==6) building the rotary cos/sin table (bit-identical
// math to the original per-lane computation).
// ---------------------------------------------------------------------------
__global__ __launch_bounds__(256) void cast6(
    const float* __restrict__ x,  const float* __restrict__ Wq,
    const float* __restrict__ Wk, const float* __restrict__ Wv,
    const float* __restrict__ Wg, const float* __restrict__ Wo,
    bf16* __restrict__ xb,  bf16* __restrict__ Wqb,
    bf16* __restrict__ Wkb, bf16* __restrict__ Wvb,
    bf16* __restrict__ Wgb, bf16* __restrict__ Wob,
    float* __restrict__ rc, float* __restrict__ rs) {
    if (blockIdx.y == 6) {
        const int idx = blockIdx.x * 256 + threadIdx.x;
        if (idx < S_LEN * 32) {
            const int s = idx >> 5, i = idx & 31;
            float af  = (float)(((double)(2 * i) / 64.0) * 3.14159265358979323846);
            float ang = (float)s * af;
            float radius = 1.0f / (1.0f + 0.01f * (float)s);
            rc[idx] = radius * (float)cos((double)ang);
            rs[idx] = radius * (float)sin((double)ang);
        }
        return;
    }
    const float* s; bf16* d; int n;
    switch (blockIdx.y) {
        case 0: s = x;  d = xb;  n = S_LEN * DIM; break;
        case 1: s = Wq; d = Wqb; n = DIM * DIM;   break;
        case 2: s = Wk; d = Wkb; n = KVDIM * DIM; break;
        case 3: s = Wv; d = Wvb; n = KVDIM * DIM; break;
        case 4: s = Wg; d = Wgb; n = KVDIM * DIM; break;
        default: s = Wo; d = Wob; n = DIM * DIM;  break;
    }
    for (int i = (blockIdx.x * 256 + threadIdx.x) * 4; i < n; i += gridDim.x * 1024) {
        float4 v = *(const float4*)(s + i);
        d[i]     = __float2bfloat16(v.x);
        d[i + 1] = __float2bfloat16(v.y);
        d[i + 2] = __float2bfloat16(v.z);
        d[i + 3] = __float2bfloat16(v.w);
    }
}

// ---------------------------------------------------------------------------
// R1-verified 64x64 GEMM core (gload_lds staging, XOR-swizzled both sides):
// C[M,N] = A[M,K]*B[N,K]^T, fp32 out. Used by gemm_out only.
// ---------------------------------------------------------------------------
__device__ __forceinline__ void gemm_core(
    const bf16* __restrict__ A, const bf16* __restrict__ B,
    float* __restrict__ C, int bm, int bn, int N, int K) {
    __shared__ bf16 As[64 * 64];
    __shared__ bf16 Bs[64 * 64];
    const int tid  = threadIdx.x;
    const int w    = tid >> 6;
    const int lane = tid & 63;
    const int quad = lane >> 4;
    const int lm   = lane & 15;
    const int srow = tid >> 3;
    const int sseg = (tid & 7) ^ (srow & 7);
    const bf16* a0p = A + (size_t)(bm + srow) * K + (sseg << 3);
    const bf16* a1p = a0p + (size_t)32 * K;
    const bf16* b0p = B + (size_t)(bn + srow) * K + (sseg << 3);
    const bf16* b1p = b0p + (size_t)32 * K;
    bf16* ldsA = As + w * 512;
    bf16* ldsB = Bs + w * 512;

    f32x4 acc[4] = {};
    const int ra  = w * 16 + lm;
    const int rax = ra & 7;
    const int aoff0 = ra * 64 + (((quad    ) ^ rax) << 3);
    const int aoff1 = ra * 64 + (((quad + 4) ^ rax) << 3);
    const int rbx = lm & 7;
    const int boff0 = lm * 64 + (((quad    ) ^ rbx) << 3);
    const int boff1 = lm * 64 + (((quad + 4) ^ rbx) << 3);

    for (int k0 = 0; k0 < K; k0 += 64) {
        gload_lds16(a0p + k0, ldsA);
        gload_lds16(a1p + k0, ldsA + 2048);
        gload_lds16(b0p + k0, ldsB);
        gload_lds16(b1p + k0, ldsB + 2048);
        __syncthreads();
        short8 a0 = *(const short8*)&As[aoff0];
        short8 a1 = *(const short8*)&As[aoff1];
        #pragma unroll
        for (int t = 0; t < 4; ++t) {
            short8 b0 = *(const short8*)&Bs[boff0 + t * 16 * 64];
            short8 b1 = *(const short8*)&Bs[boff1 + t * 16 * 64];
            acc[t] = __builtin_amdgcn_mfma_f32_16x16x32_bf16(a0, b0, acc[t], 0, 0, 0);
            acc[t] = __builtin_amdgcn_mfma_f32_16x16x32_bf16(a1, b1, acc[t], 0, 0, 0);
        }
        __syncthreads();
    }
    const int r0 = bm + w * 16 + quad * 4;
    #pragma unroll
    for (int t = 0; t < 4; ++t) {
        const int col = bn + t * 16 + lm;
        #pragma unroll
        for (int i = 0; i < 4; ++i)
            C[(size_t)(r0 + i) * N + col] = acc[t][i];
    }
}

__global__ __launch_bounds__(256) void gemm_out(
    const bf16* __restrict__ Yb, const bf16* __restrict__ Wob,
    float* __restrict__ C) {
    gemm_core(Yb, Wob, C, blockIdx.y * 64, blockIdx.x * 64, DIM, DIM);
}

// ---------------------------------------------------------------------------
// FUSED Q/K/V/G projection + postproc. Same 64x64 core; epilogue applies
// RMSNorm+rotary(+gain) for Q/K tiles (each tile IS one head's 64 cols) and
// V*sigmoid(G) for VG tiles (block computes BOTH V and G via a 2nd B tile).
// All epilogue math is bit-identical to the old postproc_pk:
//  - sum-of-squares tree: o=32 pair = acc[t]^acc[t^2] (in-register),
//    o=16 = t^1 (in-register), o=8/4/2/1 = shfl within the 16-lane m-group
//    (commutative reorder only -> same bits).
//  - rotary partner d<->d+-32 = acc[t^2] on the SAME lane; same rc/rs table.
// grid.x: 0-3 = VG (heavy, launched first), 4-7 = K, 8-23 = Q.
// ---------------------------------------------------------------------------
__global__ __launch_bounds__(256) void gemm_qkvg_post(
    const bf16* __restrict__ xb,  const bf16* __restrict__ Wqb,
    const bf16* __restrict__ Wkb, const bf16* __restrict__ Wvb,
    const bf16* __restrict__ Wgb,
    bf16* __restrict__ Qb, bf16* __restrict__ Kpk, bf16* __restrict__ Vpk,
    const float* __restrict__ qgain,
    const float* __restrict__ rc, const float* __restrict__ rs) {
    __shared__ bf16 As[64 * 64];
    __shared__ bf16 Bs[64 * 64];
    __shared__ bf16 Gs[64 * 64];
    const int cx = blockIdx.x;
    const int bm = blockIdx.y * 64;
    const int tid  = threadIdx.x;
    const int w    = tid >> 6;
    const int lane = tid & 63;
    const int quad = lane >> 4;
    const int lm   = lane & 15;
    const int srow = tid >> 3;
    const int sseg = (tid & 7) ^ (srow & 7);

    int mode, bn;                       // 0=Q, 1=K, 2=VG (block-uniform)
    const bf16 *B0, *B1;
    if (cx < 4)      { mode = 2; bn = cx * 64;        B0 = Wvb; B1 = Wgb; }
    else if (cx < 8) { mode = 1; bn = (cx - 4) * 64;  B0 = Wkb; B1 = Wkb; }
    else             { mode = 0; bn = (cx - 8) * 64;  B0 = Wqb; B1 = Wqb; }

    const bf16* a0p = xb + (size_t)(bm + srow) * DIM + (sseg << 3);
    const bf16* a1p = a0p + (size_t)32 * DIM;
    const bf16* b0p = B0 + (size_t)(bn + srow) * DIM + (sseg << 3);
    const bf16* b1p = b0p + (size_t)32 * DIM;
    const bf16* g0p = B1 + (size_t)(bn + srow) * DIM + (sseg << 3);
    const bf16* g1p = g0p + (size_t)32 * DIM;
    bf16* ldsA = As + w * 512;
    bf16* ldsB = Bs + w * 512;
    bf16* ldsG = Gs + w * 512;

    f32x4 acc[4]  = {};
    f32x4 acc2[4] = {};
    const int ra  = w * 16 + lm;
    const int rax = ra & 7;
    const int aoff0 = ra * 64 + (((quad    ) ^ rax) << 3);
    const int aoff1 = ra * 64 + (((quad + 4) ^ rax) << 3);
    const int rbx = lm & 7;
    const int boff0 = lm * 64 + (((quad    ) ^ rbx) << 3);
    const int boff1 = lm * 64 + (((quad + 4) ^ rbx) << 3);

    for (int k0 = 0; k0 < DIM; k0 += 64) {
        gload_lds16(a0p + k0, ldsA);
        gload_lds16(a1p + k0, ldsA + 2048);
        gload_lds16(b0p + k0, ldsB);
        gload_lds16(b1p + k0, ldsB + 2048);
        if (mode == 2) {
            gload_lds16(g0p + k0, ldsG);
            gload_lds16(g1p + k0, ldsG + 2048);
        }
        __syncthreads();
        short8 a0 = *(const short8*)&As[aoff0];
        short8 a1 = *(const short8*)&As[aoff1];
        #pragma unroll
        for (int t = 0; t < 4; ++t) {
            short8 b0 = *(const short8*)&Bs[boff0 + t * 16 * 64];
            short8 b1 = *(const short8*)&Bs[boff1 + t * 16 * 64];
            acc[t] = __builtin_amdgcn_mfma_f32_16x16x32_bf16(a0, b0, acc[t], 0, 0, 0);
            acc[t] = __builtin_amdgcn_mfma_f32_16x16x32_bf16(a1, b1, acc[t], 0, 0, 0);
        }
        if (mode == 2) {
            #pragma unroll
            for (int t = 0; t < 4; ++t) {
                short8 g0 = *(const short8*)&Gs[boff0 + t * 16 * 64];
                short8 g1 = *(const short8*)&Gs[boff1 + t * 16 * 64];
                acc2[t] = __builtin_amdgcn_mfma_f32_16x16x32_bf16(a0, g0, acc2[t], 0, 0, 0);
                acc2[t] = __builtin_amdgcn_mfma_f32_16x16x32_bf16(a1, g1, acc2[t], 0, 0, 0);
            }
        }
        __syncthreads();
    }

    const int r0 = bm + w * 16 + quad * 4;
    if (mode == 2) {
        const int kvh = cx;
        #pragma unroll
        for (int t = 0; t < 4; ++t) {
            const int d = t * 16 + lm;
            const int half = d >> 5, d32 = d & 31;
            #pragma unroll
            for (int i = 0; i < 4; ++i) {
                const int s = r0 + i;
                float val = acc[t][i] / (1.0f + __expf(-acc2[t][i]));
                const size_t vi = (((((size_t)(kvh*2 + half)*64 + (s>>5))*2 + (d32>>4))*64)
                                   + ((s&31)>>3)*16 + (d32&15))*8 + (s&7);
                Vpk[vi] = __float2bfloat16(val);
            }
        }
    } else {
        const float gain = (mode == 0) ? qgain[cx - 8] : 1.0f;
        float rr[4];
        #pragma unroll
        for (int i = 0; i < 4; ++i) {
            float v0 = acc[0][i] * acc[0][i] + acc[2][i] * acc[2][i];
            float v1 = acc[1][i] * acc[1][i] + acc[3][i] * acc[3][i];
            float ssv = v0 + v1;
            ssv += __shfl_xor(ssv, 8);
            ssv += __shfl_xor(ssv, 4);
            ssv += __shfl_xor(ssv, 2);
            ssv += __shfl_xor(ssv, 1);
            rr[i] = rsqrtf(ssv * (1.0f/64.0f) + 1.1920928955078125e-7f);
        }
        #pragma unroll
        for (int t = 0; t < 4; ++t) {
            const int d = t * 16 + lm;
            #pragma unroll
            for (int i = 0; i < 4; ++i) {
                const int s = r0 + i;
                float n  = acc[t][i]     * rr[i];
                float no = acc[t ^ 2][i] * rr[i];
                const int ri = s * 32 + (d & 31);
                float c = rc[ri], sn = rs[ri];
                float val = (t < 2) ? (n * c + no * sn) * gain
                                    : (n * c + -no * sn) * gain;
                if (mode == 0) {
                    Qb[(size_t)s * DIM + (cx - 8) * 64 + d] = __float2bfloat16(val);
                } else {
                    const int kvh = cx - 4;
                    const int half = d >> 5, d32 = d & 31;
                    const size_t ki = (((((size_t)(kvh*2 + half)*64 + (s>>5))*2 + ((s&31)>>4))*64)
                                       + (d32>>3)*16 + (s&15))*8 + (d32&7);
                    Kpk[ki] = __float2bfloat16(val);
                }
            }
        }
    }
}

// ---------------------------------------------------------------------------
// MFMA flash attention v3 (unchanged, verified): 1 wave per block, grid 4096.
// ---------------------------------------------------------------------------
__global__ __launch_bounds__(64, 4) void attn_mfma(
    const bf16* __restrict__ Qb, const bf16* __restrict__ Kpk,
    const bf16* __restrict__ Vpk, float* __restrict__ Ao) {
    __shared__ short PW[640];             // 16 rows x 40 shorts
    const int id    = blockIdx.x;
    const int qtile = 127 - (id >> 5);
    const int hh    = id & 31;
    const int h     = hh >> 1;
    const int half  = hh & 1;
    const int kvh   = h >> 2;
    const int lane  = threadIdx.x;
    const int quad  = lane >> 4;
    const int m     = lane & 15;
    bf16* PWb = (bf16*)PW;

    const int qrow = qtile * 16 + m;
    short8 qf = *(const short8*)(Qb + (size_t)qrow * DIM + h * HD + half * 32 + quad * 8);

    const bf16* kbase = Kpk + (size_t)(kvh * 2 + half) * 64 * 1024 + lane * 8;
    const bf16* vbase = Vpk + (size_t)(kvh * 2 + half) * 64 * 1024 + lane * 8;

    f32x4 o0 = {}, o1 = {};
    float lpart[4] = {0.f, 0.f, 0.f, 0.f};
    const float scale = 0.17677669529663687f;   // 1/sqrt(32)
    const int rbase = qtile * 16 + quad * 4;
    const int nkt = (qtile >> 1) + 1;

    for (int kb = 0; kb < nkt; ++kb) {
        short8 kf0 = *(const short8*)(kbase + kb * 1024);
        short8 kf1 = *(const short8*)(kbase + kb * 1024 + 512);
        f32x4 s0 = {}, s1 = {};
        s0 = __builtin_amdgcn_mfma_f32_16x16x32_bf16(qf, kf0, s0, 0, 0, 0);
        s1 = __builtin_amdgcn_mfma_f32_16x16x32_bf16(qf, kf1, s1, 0, 0, 0);
        short8 vtf0 = *(const short8*)(vbase + kb * 1024);
        short8 vtf1 = *(const short8*)(vbase + kb * 1024 + 512);
        const int kg = kb * 32 + m;
        #pragma unroll
        for (int r = 0; r < 4; ++r) {
            const int rg = rbase + r;
            const float p0 = (kg > rg)      ? 0.f : __expf(s0[r] * scale);
            const float p1 = (kg + 16 > rg) ? 0.f : __expf(s1[r] * scale);
            lpart[r] += p0 + p1;
            PWb[(quad * 4 + r) * 40 + m]      = __float2bfloat16(p0);
            PWb[(quad * 4 + r) * 40 + 16 + m] = __float2bfloat16(p1);
        }
        asm volatile("s_waitcnt lgkmcnt(0)" ::: "memory");
        short8 pf = *(const short8*)&PW[m * 40 + quad * 8];
        o0 = __builtin_amdgcn_mfma_f32_16x16x32_bf16(pf, vtf0, o0, 0, 0, 0);
        o1 = __builtin_amdgcn_mfma_f32_16x16x32_bf16(pf, vtf1, o1, 0, 0, 0);
    }

    #pragma unroll
    for (int r = 0; r < 4; ++r) {
        float v = lpart[r];
        v += __shfl_xor(v, 1);
        v += __shfl_xor(v, 2);
        v += __shfl_xor(v, 4);
        v += __shfl_xor(v, 8);
        lpart[r] = 1.f / v;
    }
    #pragma unroll
    for (int r = 0; r < 4; ++r) {
        float* op = Ao + (size_t)(rbase + r) * DIM + h * HD + half * 32;
        op[m]      = o0[r] * lpart[r];
        op[16 + m] = o1[r] * lpart[r];
    }
}

// ---------------------------------------------------------------------------
// Combine -> bf16 Y (verified)
// ---------------------------------------------------------------------------
__global__ __launch_bounds__(256) void combine_kernel(
    const float* __restrict__ A, const float* __restrict__ lambda_p,
    bf16* __restrict__ Y) {
    const int idx = blockIdx.x * 256 + threadIdx.x;
    const int c = idx & (DIM - 1);
    const int s = idx >> 10;
    const int hh = c >> 6;
    const int d = c & 63;
    const float* base = A + (size_t)s * DIM + hh * HD;
    const float lam = lambda_p[hh];
    float y;
    if (d < 32) y = base[d]      - lam * base[d + 32];
    else        y = base[d - 32] + lam * base[d];
    Y[idx] = __float2bfloat16(y);
}

// ---------------------------------------------------------------------------
// Workspace (31.5 MB):
//  0-4    Qb bf16 (step1 write, step3 read) -> Yb overlays (step4 w, step5 r)
//  8-9    Kpk bf16 | 9-10 Vpk bf16 (step1 write, step3 read)
//  14-14.5 rc/rs rotary table (step0 w, step1 r; dead before attn)
//  14-22  Ao fp32 (step3 write, step4 read; overlays dead rc/rs)
//  22-26  xb bf16 (step0 w, step1 r)
//  26-28  Wqb | 28-28.5 Wkb | 28.5-29 Wvb | 29-29.5 Wgb | 29.5-31.5 Wob
// ---------------------------------------------------------------------------
extern "C" void kernel_launch(void* const* d_in, const int* in_sizes, int n_in,
                              void* d_out, int out_size, void* d_ws, size_t ws_size,
                              hipStream_t stream) {
    const float* x  = (const float*)d_in[0];
    const float* Wq = (const float*)d_in[1];
    const float* Wk = (const float*)d_in[2];
    const float* Wv = (const float*)d_in[3];
    const float* Wg = (const float*)d_in[4];
    const float* Wo = (const float*)d_in[5];
    const float* qg = (const float*)d_in[6];
    const float* lp = (const float*)d_in[7];
    float* out = (float*)d_out;

    char* ws = (char*)d_ws;
    bf16* Qb   = (bf16*)ws;
    bf16* Kpk  = (bf16*)(ws + (8u << 20));
    bf16* Vpk  = (bf16*)(ws + (9u << 20));
    float* rc  = (float*)(ws + (14u << 20));
    float* rs  = (float*)(ws + (14u << 20) + (256u << 10));
    float* Ao  = (float*)(ws + (14u << 20));   // overlays dead rc/rs
    bf16* xb   = (bf16*)(ws + (22u << 20));
    bf16* Wqb  = (bf16*)(ws + (26u << 20));
    bf16* Wkb  = (bf16*)(ws + (28u << 20));
    bf16* Wvb  = (bf16*)(ws + (28u << 20) + (512u << 10));
    bf16* Wgb  = (bf16*)(ws + (29u << 20));
    bf16* Wob  = (bf16*)(ws + (29u << 20) + (512u << 10));
    bf16* Yb   = (bf16*)ws;                    // overlays dead Qb

    // 0. Cast inputs to bf16 + rotary table build
    cast6<<<dim3(512, 7), 256, 0, stream>>>(x, Wq, Wk, Wv, Wg, Wo,
                                            xb, Wqb, Wkb, Wvb, Wgb, Wob, rc, rs);

    // 1. Fused Q/K/V/G projection + RMSNorm/rotary/gate epilogue
    //    grid x: 0-3 VG (heavy first), 4-7 K, 8-23 Q; y: 32 row-tiles.
    gemm_qkvg_post<<<dim3(24, S_LEN/64), 256, 0, stream>>>(
        xb, Wqb, Wkb, Wvb, Wgb, Qb, Kpk, Vpk, qg, rc, rs);

    // 2. MFMA flash attention (4096 single-wave blocks, coalesced frags)
    attn_mfma<<<4096, 64, 0, stream>>>(Qb, Kpk, Vpk, Ao);

    // 3. Lambda combine -> bf16 Y (overlays dead Qb)
    combine_kernel<<<S_LEN * DIM / 256, 256, 0, stream>>>(Ao, lp, Yb);

    // 4. MFMA output projection -> fp32 out (512 blocks of 64x64)
    gemm_out<<<dim3(DIM/64, S_LEN/64), 256, 0, stream>>>(Yb, Wob, out);
}